// Round 9
// baseline (56.031 us; speedup 1.0000x reference)
//
#include <hip/hip_runtime.h>
#include <hip/hip_bf16.h>

#define HWD 128
#define NCH 64
#define NK  9

typedef __attribute__((ext_vector_type(8))) _Float16 h16x8;
typedef __attribute__((ext_vector_type(4))) float f32x4;

// async 16B global->LDS copy (dest = wave-uniform base + lane*16, linear)
__device__ __forceinline__ void async_copy16(void* lds, const void* g) {
  __builtin_amdgcn_global_load_lds(
      (const __attribute__((address_space(1))) unsigned int*)g,
      (__attribute__((address_space(3))) unsigned int*)lds, 16, 0, 0);
}

__device__ __forceinline__ int swz(int unit, int c) { return (c ^ unit) & 7; }

// ---- merged weight prep:
// w_def [64o][64c][3][3] f32 -> wbt [9k][64o][64c] fp16
// w_off [18o][64c][3][3] f32 -> wbo [9k][32o_pad][64c] fp16
__global__ void prep_weights_kernel(const float* __restrict__ wd,
                                    const float* __restrict__ wo,
                                    _Float16* __restrict__ wbt,
                                    _Float16* __restrict__ wbo) {
  int i = blockIdx.x * 256 + threadIdx.x;
  if (i < NK * 64 * 64) {
    int c = i & 63, o = (i >> 6) & 63, k = i >> 12;
    wbt[i] = (_Float16)wd[(o * 64 + c) * 9 + k];
  } else {
    int j = i - NK * 64 * 64;
    if (j < NK * 32 * 64) {
      int c = j & 63, o = (j >> 6) & 31, k = j >> 11;
      wbo[j] = (o < 18) ? (_Float16)wo[(o * 64 + c) * 9 + k] : (_Float16)0;
    }
  }
}

// ---- x NCHW f32 -> xt NHWC fp16 ----
__global__ __launch_bounds__(256) void transpose_x_kernel(const float* __restrict__ x,
                                                          _Float16* __restrict__ xt) {
  __shared__ float tile[64][129];
  int bid = blockIdx.x;
  int b = bid >> 7, h = bid & 127;
  int t = threadIdx.x;
  const float* xb = x + ((size_t)b * NCH) * HWD * HWD + (size_t)h * HWD;
  #pragma unroll 4
  for (int i = 0; i < 32; ++i) {
    int c = (t >> 7) + 2 * i;
    int w = t & 127;
    tile[c][w] = xb[(size_t)c * HWD * HWD + w];
  }
  __syncthreads();
  _Float16* xto = xt + (((size_t)b * HWD + h) * HWD) * NCH;
  #pragma unroll 4
  for (int i = 0; i < 32; ++i) {
    int idx = i * 256 + t;
    int c = idx & 63, w = idx >> 6;
    xto[(size_t)w * NCH + c] = (_Float16)tile[c][w];
  }
}

// ---- fused kernel v9: 8x16 patch (128 px), each wave owns 2 image-rows.
// Weight A-frags read ONCE per tap and reused for both rows (halves the
// dominant LDS weight traffic). Direct global epilogue. 51.7 KB -> 3 blk/CU.
#define PH 8
#define PW 16
#define XR 12
#define XC 20
#define NSLOT (XR * XC)     // 240 slots, 64 halves each (128 B)

__global__ __launch_bounds__(256, 3) void fused_deform_kernel(
    const _Float16* __restrict__ xt, const _Float16* __restrict__ wbt,
    const _Float16* __restrict__ wbo, const float* __restrict__ bo,
    float* __restrict__ out)
{
  __shared__ _Float16 xlds[NSLOT * 64];    // 30720 B
  __shared__ _Float16 wlds[2 * 64 * 64];   // 16384 B: two 8 KB weight buffers
  __shared__ _Float16 off_h[128 * 18];     //  4608 B

  int bid = blockIdx.x;
  int cid = (bid & 7) * 128 + (bid >> 3);  // XCD swizzle (bijective, 1024 % 8 == 0)
  int wp = cid & 7;
  int hp = (cid >> 3) & 15;
  int b  = cid >> 7;
  int h0 = hp * PH, w0 = wp * PW;

  int t = threadIdx.x;
  int lane = t & 63;
  int wv = t >> 6;
  int pl = lane & 15;
  int cg = lane >> 4;
  int w = w0 + pl;

  const _Float16* xtb = xt + ((size_t)b * HWD * HWD) * NCH;

  // ---- stage x halo tile (async, source pre-swizzled, dest linear) ----
  #pragma unroll
  for (int i = 0; i < 8; ++i) {
    int idx = i * 256 + t;                 // 240 slots * 8 chunks = 1920
    if (idx < NSLOT * 8) {
      int px = idx >> 3, c8 = idx & 7;
      int r = px / XC, c = px - r * XC;
      int yr = min(max(h0 - 2 + r, 0), HWD - 1);
      int xc = min(max(w0 - 2 + c, 0), HWD - 1);
      async_copy16(xlds + idx * 8,
                   xtb + (size_t)(yr * HWD + xc) * NCH + swz(px, c8) * 8);
    }
  }

  // ---- weight stagers: one tap into buffer buf (async, swizzled source) ----
  auto stage_wbo_tap = [&](int k, int buf) {       // 32 rows x 8 chunks = 256
    int row = t >> 3, c8 = t & 7;
    async_copy16(wlds + buf * 4096 + t * 8,
                 wbo + ((size_t)k * 32 + row) * 64 + swz(row, c8) * 8);
  };
  auto stage_wbt_tap = [&](int k, int buf) {       // 64 rows x 8 chunks = 512
    #pragma unroll
    for (int i = 0; i < 2; ++i) {
      int idx = i * 256 + t;
      int row = idx >> 3, c8 = idx & 7;
      async_copy16(wlds + buf * 4096 + idx * 8,
                   wbt + ((size_t)k * 64 + row) * 64 + swz(row, c8) * 8);
    }
  };

  auto rdw = [&](const _Float16* base, int row, int cq) {
    return *(const h16x8*)(base + row * 64 + swz(row, cq) * 8);
  };

  stage_wbo_tap(0, 0);
  __syncthreads();    // all staging (x halo + wbo tap0) complete

  // ======== PHASE 1: offset conv ========
  f32x4 acco[2][2];   // [pg][nt]
  #pragma unroll
  for (int pg = 0; pg < 2; ++pg)
    #pragma unroll
    for (int nt = 0; nt < 2; ++nt) acco[pg][nt] = (f32x4){0.f, 0.f, 0.f, 0.f};

  auto tap1 = [&](int k, int buf) {
    int ky = k / 3, kx = k - ky * 3;
    const _Float16* wb = wlds + buf * 4096;
    h16x8 a0[2], a1[2];
    #pragma unroll
    for (int nt = 0; nt < 2; ++nt) {
      a0[nt] = rdw(wb, nt * 16 + pl, cg);
      a1[nt] = rdw(wb, nt * 16 + pl, cg + 4);
    }
    #pragma unroll
    for (int pg = 0; pg < 2; ++pg) {
      int prow = wv * 2 + pg;
      int y = h0 + prow + ky - 1, x = w + kx - 1;
      bool ok = (y >= 0) & (y < HWD) & (x >= 0) & (x < HWD);
      int slot = (prow + 1 + ky) * XC + (pl + 1 + kx);
      const _Float16* sp = xlds + slot * 64;
      h16x8 b0 = *(const h16x8*)(sp + swz(slot, cg) * 8);
      h16x8 b1 = *(const h16x8*)(sp + swz(slot, cg + 4) * 8);
      if (!ok) {
        #pragma unroll
        for (int j = 0; j < 8; ++j) { b0[j] = (_Float16)0; b1[j] = (_Float16)0; }
      }
      #pragma unroll
      for (int nt = 0; nt < 2; ++nt) {
        acco[pg][nt] = __builtin_amdgcn_mfma_f32_16x16x32_f16(a0[nt], b0, acco[pg][nt], 0, 0, 0);
        acco[pg][nt] = __builtin_amdgcn_mfma_f32_16x16x32_f16(a1[nt], b1, acco[pg][nt], 0, 0, 0);
      }
    }
  };

  #pragma unroll
  for (int k = 0; k < NK; ++k) {
    if (k < NK - 1) stage_wbo_tap(k + 1, (k + 1) & 1);
    tap1(k, k & 1);
    __syncthreads();
  }

  // prefetch wbt tap0 into buf0 (last read of buf0 was tap1(8), barrier passed)
  stage_wbt_tap(0, 0);

  // write offsets (fp16): D col=pixel (lane&15), row=oc (cg*4+r+16nt)
  #pragma unroll
  for (int pg = 0; pg < 2; ++pg) {
    int p = (wv * 2 + pg) * 16 + pl;
    #pragma unroll
    for (int nt = 0; nt < 2; ++nt) {
      #pragma unroll
      for (int r = 0; r < 4; ++r) {
        int oc = nt * 16 + cg * 4 + r;
        if (oc < 18)
          off_h[p * 18 + oc] = (_Float16)(acco[pg][nt][r] + bo[oc]);
      }
    }
  }
  __syncthreads();    // off_h visible + wbt tap0 staged

  // ======== PHASE 2: deformable conv ========
  float oys[2][NK], oxs[2][NK];
  #pragma unroll
  for (int k = 0; k < NK; ++k) {
    #pragma unroll
    for (int pg = 0; pg < 2; ++pg) {
      int p = (wv * 2 + pg) * 16 + pl;
      oys[pg][k] = (float)off_h[p * 18 + 2 * k];
      oxs[pg][k] = (float)off_h[p * 18 + 2 * k + 1];
    }
  }

  f32x4 acc[2][4];    // [pg][nt]
  #pragma unroll
  for (int pg = 0; pg < 2; ++pg)
    #pragma unroll
    for (int nt = 0; nt < 4; ++nt) acc[pg][nt] = (f32x4){0.f, 0.f, 0.f, 0.f};

  auto gather = [&](int prow, float oy, float ox, int ky, int kx,
                    h16x8& s0, h16x8& s1) {
    float py = oy + (float)(h0 + prow - 1 + ky);
    float pxf = ox + (float)(w - 1 + kx);
    float y0f = floorf(py), x0f = floorf(pxf);
    float wy1 = py - y0f, wx1 = pxf - x0f;
    float wy0 = 1.f - wy1, wx0 = 1.f - wx1;
    int y0 = (int)y0f, x0 = (int)x0f;
    int sy = y0 - (h0 - 2);
    int sx = x0 - (w0 - 2);

    #pragma unroll
    for (int j = 0; j < 8; ++j) { s0[j] = (_Float16)0; s1[j] = (_Float16)0; }

    #pragma unroll
    for (int r = 0; r < 4; ++r) {
      int dy = r >> 1, dx = r & 1;
      int yy = y0 + dy, xx = x0 + dx;
      int sr = sy + dy, sc = sx + dx;
      bool okimg = (yy >= 0) & (yy < HWD) & (xx >= 0) & (xx < HWD);
      float wtf = (dy ? wy1 : wy0) * (dx ? wx1 : wx0);
      wtf = okimg ? wtf : 0.f;
      _Float16 wzh = (_Float16)wtf;

      h16x8 g0, g1;
      bool intile = (sr >= 0) & (sr < XR) & (sc >= 0) & (sc < XC);
      if (intile) {
        int slot = sr * XC + sc;
        const _Float16* sp = xlds + slot * 64;
        g0 = *(const h16x8*)(sp + swz(slot, cg) * 8);
        g1 = *(const h16x8*)(sp + swz(slot, cg + 4) * 8);
      } else {
        // rare fallback (|offset| > ~1) or OOB-with-wt0; clamped safe read
        int yc = min(max(yy, 0), HWD - 1);
        int xc2 = min(max(xx, 0), HWD - 1);
        const _Float16* sp = xtb + (size_t)(yc * HWD + xc2) * NCH + cg * 8;
        g0 = *(const h16x8*)(sp);
        g1 = *(const h16x8*)(sp + 32);
      }
      h16x8 wzv;
      #pragma unroll
      for (int j = 0; j < 8; ++j) wzv[j] = wzh;
      s0 = g0 * wzv + s0;     // v_pk_fma_f16
      s1 = g1 * wzv + s1;
    }
  };

  auto tap2 = [&](int k, int buf) {
    int ky = k / 3, kx = k - ky * 3;
    h16x8 s0[2], s1[2];
    #pragma unroll
    for (int pg = 0; pg < 2; ++pg)
      gather(wv * 2 + pg, oys[pg][k], oxs[pg][k], ky, kx, s0[pg], s1[pg]);
    const _Float16* wb = wlds + buf * 4096;
    #pragma unroll
    for (int nt = 0; nt < 4; ++nt) {
      h16x8 a0 = rdw(wb, nt * 16 + pl, cg);       // read ONCE,
      h16x8 a1 = rdw(wb, nt * 16 + pl, cg + 4);   // used for both rows
      #pragma unroll
      for (int pg = 0; pg < 2; ++pg) {
        acc[pg][nt] = __builtin_amdgcn_mfma_f32_16x16x32_f16(a0, s0[pg], acc[pg][nt], 0, 0, 0);
        acc[pg][nt] = __builtin_amdgcn_mfma_f32_16x16x32_f16(a1, s1[pg], acc[pg][nt], 0, 0, 0);
      }
    }
  };

  #pragma unroll
  for (int k = 0; k < NK; ++k) {
    if (k < NK - 1) stage_wbt_tap(k + 1, (k + 1) & 1);
    tap2(k, k & 1);
    if (k < NK - 1) __syncthreads();
  }

  // ---- epilogue: direct coalesced stores (lanes 0-15 = 64B row segment) ----
  #pragma unroll
  for (int pg = 0; pg < 2; ++pg) {
    int hrow = h0 + wv * 2 + pg;
    #pragma unroll
    for (int nt = 0; nt < 4; ++nt) {
      #pragma unroll
      for (int r = 0; r < 4; ++r) {
        int oc = nt * 16 + cg * 4 + r;
        out[(((size_t)b * NCH + oc) * HWD + hrow) * HWD + w0 + pl] = acc[pg][nt][r];
      }
    }
  }
}

extern "C" void kernel_launch(void* const* d_in, const int* in_sizes, int n_in,
                              void* d_out, int out_size, void* d_ws, size_t ws_size,
                              hipStream_t stream) {
  const float* x     = (const float*)d_in[0];
  const float* w_off = (const float*)d_in[1];
  const float* b_off = (const float*)d_in[2];
  const float* w_def = (const float*)d_in[3];
  float* out = (float*)d_out;

  char* ws = (char*)d_ws;
  _Float16* xt  = (_Float16*)ws;                       // 8*128*128*64*2 = 16,777,216 B
  _Float16* wbt = (_Float16*)(ws + 16777216);          // 9*64*64*2      =     73,728 B
  _Float16* wbo = (_Float16*)(ws + 16777216 + 73728);  // 9*32*64*2      =     36,864 B

  hipLaunchKernelGGL(prep_weights_kernel, dim3(216),  dim3(256), 0, stream, w_def, w_off, wbt, wbo);
  hipLaunchKernelGGL(transpose_x_kernel,  dim3(1024), dim3(256), 0, stream, x, xt);
  hipLaunchKernelGGL(fused_deform_kernel, dim3(1024), dim3(256), 0, stream, xt, wbt, wbo, b_off, out);
}